// Round 6
// baseline (41.866 us; speedup 1.0000x reference)
//
#include <hip/hip_runtime.h>
#include <hip/hip_bf16.h>

typedef __attribute__((ext_vector_type(8))) short short8;
typedef __attribute__((ext_vector_type(16))) float f32x16;
typedef __attribute__((ext_vector_type(4))) float fx4;
typedef __attribute__((ext_vector_type(4))) unsigned uint4v;

#define LOG2E_F 1.4426950408889634f

// ws layout:
//   ushort kb   [8000][8]  bf16                        @ elem 0
//   ushort cq   [8000][8]  bf16 (pre-scaled by log2e)  @ elem 65536
//   ushort vfrag key-permuted B-frag-ready tiles       @ elem 131072
//   f32    pls  [250 qt][32 kpw][2 g][32 q]            @ f32 elem 524288  (byte 2 MiB)
//   u32    pacc [250 qt][32 kpw][32 q][32 col]         @ u32 elem 1048576 (byte 4 MiB)
//          pacc word = pk2(ctx[q][col], ctx[q][col+32])
#define KB_OFF   0u
#define CQ_OFF   65536u
#define VF_OFF   131072u
#define PLS_F    524288u
#define PACC_U   1048576u

__device__ __forceinline__ float fast_exp2(float v) {
#if __has_builtin(__builtin_amdgcn_exp2f)
    return __builtin_amdgcn_exp2f(v);
#else
    return exp2f(v);
#endif
}

__device__ __forceinline__ unsigned short f2bfu(float f) {
    unsigned short u;
    __hip_bfloat16 h = __float2bfloat16(f);
    __builtin_memcpy(&u, &h, 2);
    return u;
}

// two f32 -> one u32 of 2 bf16 (compiler fuses into v_cvt_pk_bf16_f32)
__device__ __forceinline__ unsigned pk2(float lo, float hi) {
    return (unsigned)f2bfu(lo) | ((unsigned)f2bfu(hi) << 16);
}

__device__ __forceinline__ short8 cvt8(fx4 a, fx4 b) {
    uint4v u;
    u[0] = pk2(a[0], a[1]);
    u[1] = pk2(a[2], a[3]);
    u[2] = pk2(b[0], b[1]);
    u[3] = pk2(b[2], b[3]);
    return __builtin_bit_cast(short8, u);
}

// ---------------- Phase A: MFMA projections (unchanged from R5) ----------------
__global__ __launch_bounds__(128, 1) void pam_proj(
    const float* __restrict__ x,
    const float* __restrict__ Wb,
    const float* __restrict__ Wc,
    const float* __restrict__ Wd,
    unsigned short* __restrict__ ws)
{
    __shared__ alignas(16) unsigned short Wt[96][72];   // [col][k]

    const int tid = threadIdx.x;
#pragma unroll
    for (int i = 0; i < 32; ++i) {
        int e = i * 128 + tid;
        int col = e & 63, k = e >> 6;
        Wt[16 + col][k] = f2bfu(Wd[k * 64 + col]);
    }
#pragma unroll
    for (int i = 0; i < 8; ++i) {
        int e = i * 128 + tid;
        int c = e & 15, k = e >> 4;
        float w = (c < 8) ? Wb[k * 8 + c] : Wc[k * 8 + (c - 8)] * LOG2E_F;
        Wt[c][k] = f2bfu(w);
    }
#pragma unroll
    for (int i = 0; i < 9; ++i) {
        int e = i * 128 + tid;
        if (e < 1152) Wt[80 + e / 72][e - (e / 72) * 72] = 0;
    }
    __syncthreads();

    const int wave = tid >> 6, lane = tid & 63;
    const int l31 = lane & 31, g = lane >> 5;
    const int rowbase = blockIdx.x * 64 + wave * 32;    // 125*64 = 8000 exact

    short8 bfrag[3][4];
#pragma unroll
    for (int ct = 0; ct < 3; ++ct)
#pragma unroll
        for (int kk = 0; kk < 4; ++kk)
            bfrag[ct][kk] = *reinterpret_cast<const short8*>(&Wt[ct * 32 + l31][kk * 16 + g * 8]);

    const float* xr = x + (size_t)(rowbase + l31) * 64 + g * 8;
    short8 afrag[4];
#pragma unroll
    for (int kk = 0; kk < 4; ++kk) {
        fx4 a = *reinterpret_cast<const fx4*>(xr + kk * 16);
        fx4 b = *reinterpret_cast<const fx4*>(xr + kk * 16 + 4);
        afrag[kk] = cvt8(a, b);
    }

    f32x16 acc[3] = {};
#pragma unroll
    for (int kk = 0; kk < 4; ++kk)
#pragma unroll
        for (int ct = 0; ct < 3; ++ct)
            acc[ct] = __builtin_amdgcn_mfma_f32_32x32x16_bf16(afrag[kk], bfrag[ct][kk], acc[ct], 0, 0, 0);

#pragma unroll
    for (int ct = 0; ct < 3; ++ct) {
        const int col = ct * 32 + l31;
#pragma unroll
        for (int r = 0; r < 16; ++r) {
            const int row = rowbase + (r & 3) + 8 * (r >> 2) + 4 * g;
            const unsigned short hv = f2bfu(acc[ct][r]);
            if (col < 8) {
                ws[KB_OFF + row * 8u + col] = hv;
            } else if (col < 16) {
                ws[CQ_OFF + row * 8u + (col - 8)] = hv;
            } else if (col < 80) {
                const unsigned j  = col - 16;
                const unsigned t5 = row & 31u;
                const unsigned ks = t5 >> 4;
                const unsigned rr = t5 & 15u;
                const unsigned gg = (rr >> 2) & 1u;
                const unsigned ee = (rr & 3u) + ((rr >> 3) << 2);
                ws[VF_OFF + (row >> 5) * 2048u + ks * 1024u + gg * 512u + j * 8u + ee] = hv;
            }
        }
    }
}

// ---------------- Phase B: flash attention, QW=32, 32-way key split ----------
// 2016 blocks x 4 waves = 8000 active waves (max occupancy for this VGPR
// footprint). Block = (q-group qg, key-part kpw); wave w -> qt = qg*4+w, so
// all 4 waves share kpw's V lines (L1 reuse). ~7.8 steps/wave. No LDS; each
// wave writes its own bf16-packed partial. Clamped (branch-free) prefetch.
__global__ __launch_bounds__(256, 4) void pam_attn(
    const unsigned short* __restrict__ ws,
    float* __restrict__ wsf,
    unsigned* __restrict__ wsu)
{
    const int tid  = threadIdx.x;
    const int wave = tid >> 6;
    const int lane = tid & 63;
    const int l31  = lane & 31;
    const int g    = lane >> 5;
    const int qg   = blockIdx.x >> 5;
    const int kpw  = blockIdx.x & 31;
    const int qt   = qg * 4 + wave;
    if (qt >= 250) return;                 // no barriers anywhere
    const int qbase = qt * 32;

    const short8* kbp = reinterpret_cast<const short8*>(ws + KB_OFF);
    const short8* cqp = reinterpret_cast<const short8*>(ws + CQ_OFF);
    const short8* vp  = reinterpret_cast<const short8*>(ws + VF_OFF);

    short8 cf = {};
    if (lane < 32) cf = cqp[qbase + l31];

    f32x16 acc0 = {}, acc1 = {};
    float ls0 = 0.f, ls1 = 0.f, ls2 = 0.f, ls3 = 0.f;

    const int s0 = (250 * kpw) >> 5;
    const int s1 = (250 * (kpw + 1)) >> 5;

    short8 kf = {};
    if (lane < 32) kf = kbp[s0 * 32 + l31];
    const int vb0 = s0 * 256 + g * 64 + l31;
    short8 v00 = vp[vb0];
    short8 v01 = vp[vb0 + 32];
    short8 v10 = vp[vb0 + 128];
    short8 v11 = vp[vb0 + 160];

    for (int s = s0; s < s1; ++s) {
        // branch-free prefetch: last iteration re-loads itself (harmless)
        const int sc = (s + 1 < s1) ? (s + 1) : (s1 - 1);
        short8 kfn = {};
        if (lane < 32) kfn = kbp[sc * 32 + l31];
        const int nb = sc * 256 + g * 64 + l31;
        const short8 n00 = vp[nb];
        const short8 n01 = vp[nb + 32];
        const short8 n10 = vp[nb + 128];
        const short8 n11 = vp[nb + 160];

        f32x16 z = {};
        const f32x16 st = __builtin_amdgcn_mfma_f32_32x32x16_bf16(kf, cf, z, 0, 0, 0);

        float e[16];
#pragma unroll
        for (int r = 0; r < 16; ++r) e[r] = fast_exp2(st[r]);

        ls0 += (e[0]  + e[1])  + (e[2]  + e[3]);
        ls1 += (e[4]  + e[5])  + (e[6]  + e[7]);
        ls2 += (e[8]  + e[9])  + (e[10] + e[11]);
        ls3 += (e[12] + e[13]) + (e[14] + e[15]);

        uint4v u0, u1;
#pragma unroll
        for (int p = 0; p < 4; ++p) u0[p] = pk2(e[2 * p], e[2 * p + 1]);
#pragma unroll
        for (int p = 0; p < 4; ++p) u1[p] = pk2(e[8 + 2 * p], e[9 + 2 * p]);
        const short8 af0 = __builtin_bit_cast(short8, u0);
        const short8 af1 = __builtin_bit_cast(short8, u1);

        acc0 = __builtin_amdgcn_mfma_f32_32x32x16_bf16(af0, v00, acc0, 0, 0, 0);
        acc1 = __builtin_amdgcn_mfma_f32_32x32x16_bf16(af0, v01, acc1, 0, 0, 0);
        acc0 = __builtin_amdgcn_mfma_f32_32x32x16_bf16(af1, v10, acc0, 0, 0, 0);
        acc1 = __builtin_amdgcn_mfma_f32_32x32x16_bf16(af1, v11, acc1, 0, 0, 0);

        kf = kfn; v00 = n00; v01 = n01; v10 = n10; v11 = n11;
    }

    // per-wave partial: pls[qt][kpw][g][l31], pacc[qt][kpw][q][col] packed
    const unsigned pw = (unsigned)qt * 32u + (unsigned)kpw;
    wsf[PLS_F + pw * 64u + g * 32u + l31] = (ls0 + ls1) + (ls2 + ls3);

    const unsigned pb = PACC_U + pw * 1024u;
#pragma unroll
    for (int r = 0; r < 16; ++r) {
        const int q0 = (r & 3) + 8 * (r >> 2) + 4 * g;
        wsu[pb + (unsigned)q0 * 32u + l31] = pk2(acc0[r], acc1[r]);
    }
}

// ---------------- Phase C: merge 32 partials + epilogue ----------------
// 250 blocks x 256 thr; thread = (q = tid>>3, i0 = (tid&7)*4) covers cols
// i0..i0+3 and 32+i0..32+i0+3 via the packed words.
__global__ __launch_bounds__(256) void pam_merge(
    const float* __restrict__ x,
    const float* __restrict__ gamma_p,
    const float* __restrict__ wsf,
    const unsigned* __restrict__ wsu,
    float* __restrict__ out)
{
    const int tid = threadIdx.x;
    const int qt  = blockIdx.x;
    const int q   = tid >> 3;
    const int i0  = (tid & 7) * 4;

    float lq = 0.f;
#pragma unroll
    for (int kpw = 0; kpw < 32; ++kpw) {
        const unsigned lb = PLS_F + ((unsigned)(qt * 32 + kpw)) * 64u + q;
        lq += wsf[lb] + wsf[lb + 32];
    }

    fx4 alo = {}, ahi = {};
#pragma unroll
    for (int kpw = 0; kpw < 32; ++kpw) {
        const unsigned* pb = wsu + PACC_U
            + (((unsigned)(qt * 32 + kpw)) * 32u + q) * 32u + i0;
        const uint4v w = *reinterpret_cast<const uint4v*>(pb);
#pragma unroll
        for (int t = 0; t < 4; ++t) {
            alo[t] += __builtin_bit_cast(float, w[t] << 16);
            ahi[t] += __builtin_bit_cast(float, w[t] & 0xffff0000u);
        }
    }

    const float sc = gamma_p[0] / lq;
    const int base = (qt * 32 + q) * 64;

    const fx4 x0 = *reinterpret_cast<const fx4*>(x + base + i0);
    const fx4 x1 = *reinterpret_cast<const fx4*>(x + base + 32 + i0);
    fx4 o0, o1;
#pragma unroll
    for (int t = 0; t < 4; ++t) {
        o0[t] = alo[t] * sc + x0[t];
        o1[t] = ahi[t] * sc + x1[t];
    }
    *reinterpret_cast<fx4*>(out + base + i0)      = o0;
    *reinterpret_cast<fx4*>(out + base + 32 + i0) = o1;
}

extern "C" void kernel_launch(void* const* d_in, const int* in_sizes, int n_in,
                              void* d_out, int out_size, void* d_ws, size_t ws_size,
                              hipStream_t stream)
{
    const float* x     = (const float*)d_in[0];
    const float* Wb    = (const float*)d_in[1];
    const float* Wc    = (const float*)d_in[2];
    const float* Wd    = (const float*)d_in[3];
    const float* gamma = (const float*)d_in[4];
    float* outp = (float*)d_out;
    unsigned short* ws = (unsigned short*)d_ws;
    float* wsf = (float*)d_ws;
    unsigned* wsu = (unsigned*)d_ws;

    hipLaunchKernelGGL(pam_proj, dim3(125), dim3(128), 0, stream, x, Wb, Wc, Wd, ws);
    hipLaunchKernelGGL(pam_attn, dim3(2016), dim3(256), 0, stream,
                       (const unsigned short*)ws, wsf, wsu);
    hipLaunchKernelGGL(pam_merge, dim3(250), dim3(256), 0, stream,
                       x, gamma, (const float*)wsf, (const unsigned*)wsu, outp);
}

// Round 7
// 31.487 us; speedup vs baseline: 1.3296x; 1.3296x over previous
//
#include <hip/hip_runtime.h>
#include <hip/hip_bf16.h>

typedef __attribute__((ext_vector_type(8))) short short8;
typedef __attribute__((ext_vector_type(16))) float f32x16;
typedef __attribute__((ext_vector_type(4))) float fx4;
typedef __attribute__((ext_vector_type(4))) unsigned uint4v;

#define LOG2E_F 1.4426950408889634f

// ws layout:
//   ushort kb   [8000][8]  bf16                        @ elem 0
//   ushort cq   [8000][8]  bf16 (pre-scaled by log2e)  @ elem 65536
//   ushort ZERO 16B of zeros (A-frag upper-lane pad)   @ elem 130048
//   ushort vfrag key-permuted B-frag-ready tiles       @ elem 131072
//   f32    pls  [1000 blk][32 q]                       @ f32 elem 524288 (byte 2 MiB)
//   u32    pacc [1000 blk][32 q][32 c] packed bf16     @ u32 elem 1048576 (byte 4 MiB)
//          pacc word = pk2(ctx[q][c], ctx[q][c+32])
#define KB_OFF   0u
#define CQ_OFF   65536u
#define ZERO_OFF 130048u
#define VF_OFF   131072u
#define PLS_F    524288u
#define PACC_U   1048576u

__device__ __forceinline__ float fast_exp2(float v) {
#if __has_builtin(__builtin_amdgcn_exp2f)
    return __builtin_amdgcn_exp2f(v);
#else
    return exp2f(v);
#endif
}

__device__ __forceinline__ unsigned short f2bfu(float f) {
    unsigned short u;
    __hip_bfloat16 h = __float2bfloat16(f);
    __builtin_memcpy(&u, &h, 2);
    return u;
}

// two f32 -> one u32 of 2 bf16 (compiler fuses into v_cvt_pk_bf16_f32)
__device__ __forceinline__ unsigned pk2(float lo, float hi) {
    return (unsigned)f2bfu(lo) | ((unsigned)f2bfu(hi) << 16);
}

__device__ __forceinline__ short8 cvt8(fx4 a, fx4 b) {
    uint4v u;
    u[0] = pk2(a[0], a[1]);
    u[1] = pk2(a[2], a[3]);
    u[2] = pk2(b[0], b[1]);
    u[3] = pk2(b[2], b[3]);
    return __builtin_bit_cast(short8, u);
}

// ---------------- Phase A: MFMA projections (R5 version + zero block) --------
__global__ __launch_bounds__(128, 1) void pam_proj(
    const float* __restrict__ x,
    const float* __restrict__ Wb,
    const float* __restrict__ Wc,
    const float* __restrict__ Wd,
    unsigned short* __restrict__ ws)
{
    __shared__ alignas(16) unsigned short Wt[96][72];   // [col][k]

    const int tid = threadIdx.x;
    if (tid < 8) ws[ZERO_OFF + tid] = 0;                // 16B zero page for attn
#pragma unroll
    for (int i = 0; i < 32; ++i) {
        int e = i * 128 + tid;
        int col = e & 63, k = e >> 6;
        Wt[16 + col][k] = f2bfu(Wd[k * 64 + col]);
    }
#pragma unroll
    for (int i = 0; i < 8; ++i) {
        int e = i * 128 + tid;
        int c = e & 15, k = e >> 4;
        float w = (c < 8) ? Wb[k * 8 + c] : Wc[k * 8 + (c - 8)] * LOG2E_F;
        Wt[c][k] = f2bfu(w);
    }
#pragma unroll
    for (int i = 0; i < 9; ++i) {
        int e = i * 128 + tid;
        if (e < 1152) Wt[80 + e / 72][e - (e / 72) * 72] = 0;
    }
    __syncthreads();

    const int wave = tid >> 6, lane = tid & 63;
    const int l31 = lane & 31, g = lane >> 5;
    const int rowbase = blockIdx.x * 64 + wave * 32;    // 125*64 = 8000 exact

    short8 bfrag[3][4];
#pragma unroll
    for (int ct = 0; ct < 3; ++ct)
#pragma unroll
        for (int kk = 0; kk < 4; ++kk)
            bfrag[ct][kk] = *reinterpret_cast<const short8*>(&Wt[ct * 32 + l31][kk * 16 + g * 8]);

    const float* xr = x + (size_t)(rowbase + l31) * 64 + g * 8;
    short8 afrag[4];
#pragma unroll
    for (int kk = 0; kk < 4; ++kk) {
        fx4 a = *reinterpret_cast<const fx4*>(xr + kk * 16);
        fx4 b = *reinterpret_cast<const fx4*>(xr + kk * 16 + 4);
        afrag[kk] = cvt8(a, b);
    }

    f32x16 acc[3] = {};
#pragma unroll
    for (int kk = 0; kk < 4; ++kk)
#pragma unroll
        for (int ct = 0; ct < 3; ++ct)
            acc[ct] = __builtin_amdgcn_mfma_f32_32x32x16_bf16(afrag[kk], bfrag[ct][kk], acc[ct], 0, 0, 0);

#pragma unroll
    for (int ct = 0; ct < 3; ++ct) {
        const int col = ct * 32 + l31;
#pragma unroll
        for (int r = 0; r < 16; ++r) {
            const int row = rowbase + (r & 3) + 8 * (r >> 2) + 4 * g;
            const unsigned short hv = f2bfu(acc[ct][r]);
            if (col < 8) {
                ws[KB_OFF + row * 8u + col] = hv;
            } else if (col < 16) {
                ws[CQ_OFF + row * 8u + (col - 8)] = hv;
            } else if (col < 80) {
                const unsigned j  = col - 16;
                const unsigned t5 = row & 31u;
                const unsigned ks = t5 >> 4;
                const unsigned rr = t5 & 15u;
                const unsigned gg = (rr >> 2) & 1u;
                const unsigned ee = (rr & 3u) + ((rr >> 3) << 2);
                ws[VF_OFF + (row >> 5) * 2048u + ks * 1024u + gg * 512u + j * 8u + ee] = hv;
            }
        }
    }
}

// ---------------- Phase B: flash attention (R3 grid, pipelined loop) ---------
// 1000 blocks x 4 waves; block = (qt = bid>>2, kp = bid&3); waves split the
// part's ~62 steps. Branch-free: K-prefetch uses per-lane stride-0 zero-page
// addressing for lanes>=32 (A-frag k=8..15 pad); clamped prefetch index.
// Pipelined: exp/pack consume LAST iter's QK; next QK issues before PV.
__global__ __launch_bounds__(256, 3) void pam_attn(
    const unsigned short* __restrict__ ws,
    float* __restrict__ wsf,
    unsigned* __restrict__ wsu)
{
    __shared__ alignas(16) float acc_s[4][32][64];
    __shared__ float ls_s[4][2][32];

    const int tid  = threadIdx.x;
    const int wave = tid >> 6;
    const int lane = tid & 63;
    const int l31  = lane & 31;
    const int g    = lane >> 5;
    const int qt   = blockIdx.x >> 2;
    const int kp   = blockIdx.x & 3;
    const int qbase = qt * 32;

    const short8* cqp = reinterpret_cast<const short8*>(ws + CQ_OFF);
    const short8* vp  = reinterpret_cast<const short8*>(ws + VF_OFF);

    // branch-free per-lane K addressing: lanes>=32 read the 16B zero page
    const unsigned short* kbz = ws + ((lane < 32) ? (KB_OFF + (unsigned)l31 * 8u)
                                                  : ZERO_OFF);
    const unsigned kstep = (lane < 32) ? 256u : 0u;   // ushorts per key-step

    short8 cf = {};
    if (lane < 32) cf = cqp[qbase + l31];

    f32x16 acc0 = {}, acc1 = {};
    float ls0 = 0.f, ls1 = 0.f, ls2 = 0.f, ls3 = 0.f;

    const int plen   = (kp < 2) ? 63 : 62;
    const int pstart = kp * 62 + ((kp < 2) ? kp : 2);
    const int s0 = pstart + (plen * wave) / 4;
    const int s1 = pstart + (plen * (wave + 1)) / 4;

    // prologue: load step s0, issue its QK
    short8 kf = *reinterpret_cast<const short8*>(kbz + (unsigned)s0 * kstep);
    const int vb0 = s0 * 256 + g * 64 + l31;
    short8 v00 = vp[vb0];
    short8 v01 = vp[vb0 + 32];
    short8 v10 = vp[vb0 + 128];
    short8 v11 = vp[vb0 + 160];

    const f32x16 z = {};
    f32x16 st = __builtin_amdgcn_mfma_f32_32x32x16_bf16(kf, cf, z, 0, 0, 0);

    for (int s = s0; s < s1; ++s) {
        // issue next-step loads first (clamped; last iter re-loads itself)
        const int sc = (s + 1 < s1) ? (s + 1) : (s1 - 1);
        const short8 kfn = *reinterpret_cast<const short8*>(kbz + (unsigned)sc * kstep);
        const int nb = sc * 256 + g * 64 + l31;
        const short8 n00 = vp[nb];
        const short8 n01 = vp[nb + 32];
        const short8 n10 = vp[nb + 128];
        const short8 n11 = vp[nb + 160];

        // softmax numerators from LAST-issued QK (latency already hidden)
        float e[16];
#pragma unroll
        for (int r = 0; r < 16; ++r) e[r] = fast_exp2(st[r]);

        ls0 += (e[0]  + e[1])  + (e[2]  + e[3]);
        ls1 += (e[4]  + e[5])  + (e[6]  + e[7]);
        ls2 += (e[8]  + e[9])  + (e[10] + e[11]);
        ls3 += (e[12] + e[13]) + (e[14] + e[15]);

        uint4v u0, u1;
#pragma unroll
        for (int p = 0; p < 4; ++p) u0[p] = pk2(e[2 * p], e[2 * p + 1]);
#pragma unroll
        for (int p = 0; p < 4; ++p) u1[p] = pk2(e[8 + 2 * p], e[9 + 2 * p]);
        const short8 af0 = __builtin_bit_cast(short8, u0);
        const short8 af1 = __builtin_bit_cast(short8, u1);

        // issue next QK before PV so its latency hides under PV + next loads
        const f32x16 stn = __builtin_amdgcn_mfma_f32_32x32x16_bf16(kfn, cf, z, 0, 0, 0);

        acc0 = __builtin_amdgcn_mfma_f32_32x32x16_bf16(af0, v00, acc0, 0, 0, 0);
        acc1 = __builtin_amdgcn_mfma_f32_32x32x16_bf16(af0, v01, acc1, 0, 0, 0);
        acc0 = __builtin_amdgcn_mfma_f32_32x32x16_bf16(af1, v10, acc0, 0, 0, 0);
        acc1 = __builtin_amdgcn_mfma_f32_32x32x16_bf16(af1, v11, acc1, 0, 0, 0);

        st = stn; v00 = n00; v01 = n01; v10 = n10; v11 = n11;
    }

    ls_s[wave][g][l31] = (ls0 + ls1) + (ls2 + ls3);
#pragma unroll
    for (int r = 0; r < 16; ++r) {
        const int row = (r & 3) + 8 * (r >> 2) + 4 * g;
        acc_s[wave][row][l31]      = acc0[r];
        acc_s[wave][row][32 + l31] = acc1[r];
    }
    __syncthreads();

    // deterministic merged-partial write (bf16-packed: 4.2 MB total)
    if (tid < 32) {
        float s = 0.f;
#pragma unroll
        for (int w = 0; w < 4; ++w) s += ls_s[w][0][tid] + ls_s[w][1][tid];
        wsf[PLS_F + blockIdx.x * 32u + tid] = s;
    }
    const int q = tid >> 3, c0 = (tid & 7) * 4;
    uint4v u;
#pragma unroll
    for (int t = 0; t < 4; ++t) {
        float lo = 0.f, hi = 0.f;
#pragma unroll
        for (int w = 0; w < 4; ++w) {
            lo += acc_s[w][q][c0 + t];
            hi += acc_s[w][q][32 + c0 + t];
        }
        u[t] = pk2(lo, hi);
    }
    *reinterpret_cast<uint4v*>(wsu + PACC_U + blockIdx.x * 1024u + q * 32u + c0) = u;
}

// ---------------- Phase C: merge 4 partials + epilogue ----------------
__global__ __launch_bounds__(256) void pam_merge(
    const float* __restrict__ x,
    const float* __restrict__ gamma_p,
    const float* __restrict__ wsf,
    const unsigned* __restrict__ wsu,
    float* __restrict__ out)
{
    const int tid = threadIdx.x;
    const int qt  = blockIdx.x;
    const int q   = tid >> 3;
    const int c0  = (tid & 7) * 4;

    float lq = 0.f;
#pragma unroll
    for (int kp = 0; kp < 4; ++kp)
        lq += wsf[PLS_F + (unsigned)(qt * 4 + kp) * 32u + q];

    fx4 alo = {}, ahi = {};
#pragma unroll
    for (int kp = 0; kp < 4; ++kp) {
        const uint4v w = *reinterpret_cast<const uint4v*>(
            wsu + PACC_U + (unsigned)(qt * 4 + kp) * 1024u + q * 32u + c0);
#pragma unroll
        for (int t = 0; t < 4; ++t) {
            alo[t] += __builtin_bit_cast(float, w[t] << 16);
            ahi[t] += __builtin_bit_cast(float, w[t] & 0xffff0000u);
        }
    }

    const float sc = gamma_p[0] / lq;
    const int base = (qt * 32 + q) * 64;

    const fx4 x0 = *reinterpret_cast<const fx4*>(x + base + c0);
    const fx4 x1 = *reinterpret_cast<const fx4*>(x + base + 32 + c0);
    fx4 o0, o1;
#pragma unroll
    for (int t = 0; t < 4; ++t) {
        o0[t] = alo[t] * sc + x0[t];
        o1[t] = ahi[t] * sc + x1[t];
    }
    *reinterpret_cast<fx4*>(out + base + c0)      = o0;
    *reinterpret_cast<fx4*>(out + base + 32 + c0) = o1;
}

extern "C" void kernel_launch(void* const* d_in, const int* in_sizes, int n_in,
                              void* d_out, int out_size, void* d_ws, size_t ws_size,
                              hipStream_t stream)
{
    const float* x     = (const float*)d_in[0];
    const float* Wb    = (const float*)d_in[1];
    const float* Wc    = (const float*)d_in[2];
    const float* Wd    = (const float*)d_in[3];
    const float* gamma = (const float*)d_in[4];
    float* outp = (float*)d_out;
    unsigned short* ws = (unsigned short*)d_ws;
    float* wsf = (float*)d_ws;
    unsigned* wsu = (unsigned*)d_ws;

    hipLaunchKernelGGL(pam_proj, dim3(125), dim3(128), 0, stream, x, Wb, Wc, Wd, ws);
    hipLaunchKernelGGL(pam_attn, dim3(1000), dim3(256), 0, stream,
                       (const unsigned short*)ws, wsf, wsu);
    hipLaunchKernelGGL(pam_merge, dim3(250), dim3(256), 0, stream,
                       x, gamma, (const float*)wsf, (const unsigned*)wsu, outp);
}